// Round 5
// baseline (78.834 us; speedup 1.0000x reference)
//
#include <hip/hip_runtime.h>
#include <hip/hip_bf16.h>

// B=2, M=256, N=256, K=8, P=Q=Pp=Qp=512, D=Dp=64, R=128, TEMP=8
#define LOG2E_OVER_T 0.18033688011112042f  // log2(e)/8

typedef __attribute__((ext_vector_type(8))) short short8;
typedef __attribute__((ext_vector_type(4))) float f32x4;
typedef unsigned short ushort_t;
typedef unsigned long long ull_t;

#define MFMA16(a, b, c) __builtin_amdgcn_mfma_f32_16x16x32_bf16(a, b, c, 0, 0, 0)

__device__ __forceinline__ ushort_t f2bf(float f) {
    union { float f; unsigned u; } v; v.f = f;
    unsigned r = (v.u + 0x7fffu + ((v.u >> 16) & 1u)) >> 16;
    return (ushort_t)r;
}

// split 8 fp32 -> bf16 hi (truncate) + bf16 lo (residual, truncate).
__device__ __forceinline__ void split8(const float4 a, const float4 b,
                                       short8& hi, short8& lo)
{
    union { float f[8]; unsigned u[8]; } Z;
    Z.f[0] = a.x; Z.f[1] = a.y; Z.f[2] = a.z; Z.f[3] = a.w;
    Z.f[4] = b.x; Z.f[5] = b.y; Z.f[6] = b.z; Z.f[7] = b.w;
    union { unsigned u[4]; short8 s; } H, L;
    #pragma unroll
    for (int i = 0; i < 4; i++) {
        const unsigned u0 = Z.u[2 * i], u1 = Z.u[2 * i + 1];
        H.u[i] = __builtin_amdgcn_perm(u1, u0, 0x07060302u);  // [u0.hi16, u1.hi16]
        union { unsigned u; float f; } h0, h1;
        h0.u = u0 & 0xffff0000u; h1.u = u1 & 0xffff0000u;
        union { float f; unsigned u; } l0, l1;
        l0.f = Z.f[2 * i] - h0.f; l1.f = Z.f[2 * i + 1] - h1.f;
        L.u[i] = __builtin_amdgcn_perm(l1.u, l0.u, 0x07060302u);
    }
    hi = H.s; lo = L.s;
}

// swizzle: 16B-slot index within a 512B zhl row; key = (row&7)^((row>>3)&7)
__device__ __forceinline__ int phys16(int c16, int key) {
    return (c16 & 3) | ((((c16 >> 2) ^ key) & 7) << 2);
}

// ---------------------------------------------------------------------------
// MFMA core: C[64x64] = A[64xK] * Bt[64xK]^T, bf16 in, fp32 acc. (4 waves)
// ---------------------------------------------------------------------------
__device__ __forceinline__ void mfma_core64(
    const ushort_t* __restrict__ Ag, int lda,
    const ushort_t* __restrict__ Btg, int ldb,
    int ksteps, f32x4 acc[2][2])
{
    __shared__ __align__(16) ushort_t As[64 * 40];
    __shared__ __align__(16) ushort_t Bs[64 * 40];
    const int t = threadIdx.x;
    const int srow = t >> 2, skc = (t & 3) * 8;
    const int lane = t & 63, w = t >> 6;
    const int wr = w >> 1, wc = w & 1;
    const int fr = lane & 15, kg = lane >> 4;
    const int aoff = (wr * 32 + fr) * 40 + kg * 8;
    const int boff = (wc * 32 + fr) * 40 + kg * 8;
    const long arow = (long)srow * lda + skc;
    const long brow = (long)srow * ldb + skc;

    short8 ra = *(const short8*)(Ag + arow);
    short8 rb = *(const short8*)(Btg + brow);
    for (int kt = 0; kt < ksteps; kt++) {
        __syncthreads();
        *(short8*)&As[srow * 40 + skc] = ra;
        *(short8*)&Bs[srow * 40 + skc] = rb;
        __syncthreads();
        if (kt + 1 < ksteps) {
            ra = *(const short8*)(Ag + arow + (kt + 1) * 32);
            rb = *(const short8*)(Btg + brow + (kt + 1) * 32);
        }
        short8 a0 = *(const short8*)&As[aoff];
        short8 a1 = *(const short8*)&As[aoff + 16 * 40];
        short8 b0 = *(const short8*)&Bs[boff];
        short8 b1 = *(const short8*)&Bs[boff + 16 * 40];
        acc[0][0] = MFMA16(a0, b0, acc[0][0]);
        acc[0][1] = MFMA16(a0, b1, acc[0][1]);
        acc[1][0] = MFMA16(a1, b0, acc[1][0]);
        acc[1][1] = MFMA16(a1, b1, acc[1][1]);
    }
}

__device__ __forceinline__ void zero_acc(f32x4 acc[2][2]) {
    const f32x4 z4 = {0.f, 0.f, 0.f, 0.f};
    acc[0][0] = z4; acc[0][1] = z4; acc[1][0] = z4; acc[1][1] = z4;
}

// ---------------------------------------------------------------------------
// convert: fp32 -> bf16 casts + layout permutes; also zeroes ssum.
// ---------------------------------------------------------------------------
__global__ __launch_bounds__(256)
void convert_kernel(const float* __restrict__ x_k, const float* __restrict__ y_q,
                    const float* __restrict__ Lam_x, const float* __restrict__ Theta_x,
                    const float* __restrict__ Lam_y, const float* __restrict__ Lam_zy,
                    const float* __restrict__ Lam_zx, const float* __restrict__ Theta_y,
                    ushort_t* __restrict__ xkb, ushort_t* __restrict__ yqb,
                    ushort_t* __restrict__ WxTb, ushort_t* __restrict__ WyTb,
                    ushort_t* __restrict__ Zyb, ushort_t* __restrict__ Zxb,
                    ushort_t* __restrict__ TyTb, float* __restrict__ ssum)
{
    int i = blockIdx.x * 256 + threadIdx.x;
    if (i < 262144) { xkb[i] = f2bf(x_k[i]); return; }
    i -= 262144;
    if (i < 262144) { yqb[i] = f2bf(y_q[i]); return; }
    i -= 262144;
    if (i < 524288) {  // WxTb[k][dc][p] = (dc<64 ? Lam_x : Theta_x)[k][p][dc%64]
        const int k = i >> 16, rem = i & 65535, dc = rem >> 9, p = i & 511;
        const float v = (dc < 64) ? Lam_x[((long)k * 512 + p) * 64 + dc]
                                  : Theta_x[((long)k * 512 + p) * 64 + dc - 64];
        WxTb[i] = f2bf(v); return;
    }
    i -= 524288;
    if (i < 262144) {  // WyTb[k][d][p] = Lam_y[k][p][d]
        const int k = i >> 15, d = (i >> 9) & 63, p = i & 511;
        WyTb[i] = f2bf(Lam_y[((long)k * 512 + p) * 64 + d]); return;
    }
    i -= 262144;
    if (i < 65536) { Zyb[i] = f2bf(Lam_zy[i]); return; }
    i -= 65536;
    if (i < 65536) { Zxb[i] = f2bf(Lam_zx[i]); return; }
    i -= 65536;
    if (i < 262144) {  // TyTb[q][k*64+d] = Theta_y[k][q][d]
        const int q = i >> 9, kd = i & 511, k = kd >> 6, d = kd & 63;
        TyTb[i] = f2bf(Theta_y[((long)k * 512 + q) * 64 + d]); return;
    }
    i -= 262144;
    ssum[i] = 0.f;  // 4096 entries
}

// ---------------------------------------------------------------------------
// proj: side0: [b,m] x WxT -> xtb (bf16 [bk][m][64]) + xvT (bf16 [bk][64][m])
//       side1: [b,n] x WyT -> ytb (bf16 [bk][n][64])
// ---------------------------------------------------------------------------
__global__ __launch_bounds__(256)
void proj_kernel(const ushort_t* __restrict__ xkb, const ushort_t* __restrict__ yqb,
                 const ushort_t* __restrict__ WxTb, const ushort_t* __restrict__ WyTb,
                 ushort_t* __restrict__ xtb, ushort_t* __restrict__ ytb,
                 ushort_t* __restrict__ xvTb)
{
    const int side = blockIdx.z;
    const int bx = blockIdx.x, by = blockIdx.y;
    if (side == 1 && bx >= 8) return;
    f32x4 acc[2][2]; zero_acc(acc);
    const int t = threadIdx.x, lane = t & 63, w = t >> 6;
    const int wr = w >> 1, wc = w & 1, fr = lane & 15, kg = lane >> 4;

    if (side == 0) {
        mfma_core64(xkb + (long)(by * 64) * 512, 512,
                    WxTb + (long)(bx * 64) * 512, 512, 16, acc);
        const int k = bx >> 1, isxv = bx & 1;
        #pragma unroll
        for (int mi = 0; mi < 2; mi++)
        #pragma unroll
        for (int ni = 0; ni < 2; ni++) {
            const int grow0 = by * 64 + wr * 32 + mi * 16 + kg * 4;
            const int b = grow0 >> 8, m0 = grow0 & 255;
            const int d = wc * 32 + ni * 16 + fr;
            if (!isxv) {
                #pragma unroll
                for (int j = 0; j < 4; j++)
                    xtb[(((long)(b * 8 + k)) * 256 + m0 + j) * 64 + d] = f2bf(acc[mi][ni][j]);
            } else {
                ull_t pk = (ull_t)f2bf(acc[mi][ni][0])
                         | ((ull_t)f2bf(acc[mi][ni][1]) << 16)
                         | ((ull_t)f2bf(acc[mi][ni][2]) << 32)
                         | ((ull_t)f2bf(acc[mi][ni][3]) << 48);
                *(ull_t*)&xvTb[(((long)(b * 8 + k)) * 64 + d) * 256 + m0] = pk;
            }
        }
    } else {
        mfma_core64(yqb + (long)(by * 64) * 512, 512,
                    WyTb + (long)(bx * 64) * 512, 512, 16, acc);
        const int k = bx;
        #pragma unroll
        for (int mi = 0; mi < 2; mi++)
        #pragma unroll
        for (int ni = 0; ni < 2; ni++)
        #pragma unroll
        for (int j = 0; j < 4; j++) {
            const int grow = by * 64 + wr * 32 + mi * 16 + kg * 4 + j;
            const int b = grow >> 8, n = grow & 255;
            const int d = wc * 32 + ni * 16 + fr;
            ytb[(((long)(b * 8 + k)) * 256 + n) * 64 + d] = f2bf(acc[mi][ni][j]);
        }
    }
}

// ---------------------------------------------------------------------------
// step2: wzyb[b][m][k][128] = bf16(xt @ Lam_zy^T); wzxb[b][n][k][128] likewise.
// (k-minor layout so fused_score B-frags are 16B-contiguous per k-row)
// ---------------------------------------------------------------------------
__global__ __launch_bounds__(256)
void step2_kernel(const ushort_t* __restrict__ xtb, const ushort_t* __restrict__ ytb,
                  const ushort_t* __restrict__ Zyb, const ushort_t* __restrict__ Zxb,
                  ushort_t* __restrict__ wzyb, ushort_t* __restrict__ wzxb)
{
    const int bz = blockIdx.x;  // 256
    const int which = bz >> 7, idx = bz & 127;
    const int bk = idx >> 3, tile = idx & 7, mt = tile >> 1, nt = tile & 1;
    const int k = bk & 7, b = bk >> 3;
    const ushort_t* Ag  = (which ? ytb : xtb) + ((long)bk * 256 + mt * 64) * 64;
    const ushort_t* Btg = (which ? Zxb : Zyb) + ((long)k * 128 + nt * 64) * 64;
    ushort_t* C = which ? wzxb : wzyb;
    f32x4 acc[2][2]; zero_acc(acc);
    mfma_core64(Ag, 64, Btg, 64, 2, acc);
    const int t = threadIdx.x, lane = t & 63, w = t >> 6;
    const int wr = w >> 1, wc = w & 1, fr = lane & 15, kg = lane >> 4;
    #pragma unroll
    for (int mi = 0; mi < 2; mi++)
    #pragma unroll
    for (int ni = 0; ni < 2; ni++)
    #pragma unroll
    for (int j = 0; j < 4; j++) {
        const int m_glob = mt * 64 + wr * 32 + mi * 16 + kg * 4 + j;
        const int r_glob = nt * 64 + wc * 32 + ni * 16 + fr;
        C[(((long)b * 256 + m_glob) * 8 + k) * 128 + r_glob] = f2bf(acc[mi][ni][j]);
    }
}

// ---------------------------------------------------------------------------
// fused_score v2: block (b, 8m, 32n-range), 4 chunks of 8n.
// Per chunk: z (32KB) reg-staged 1 chunk ahead -> hi/lo bf16 LDS (swizzled),
// phase2 (termB) + phase3 (termC) MFMA from LDS, xt.yt from per-block t1 LDS,
// exp -> Et bf16 + ssum atomics. z read from HBM exactly once, never re-split.
// ---------------------------------------------------------------------------
__global__ __launch_bounds__(256)
void fused_score(const float* __restrict__ z,
                 const ushort_t* __restrict__ xtb, const ushort_t* __restrict__ ytb,
                 const ushort_t* __restrict__ wzyb, const ushort_t* __restrict__ wzxb,
                 ushort_t* __restrict__ Et, float* __restrict__ ssum)
{
    const int ns = blockIdx.x;   // 0..7   n-range of 32
    const int mt = blockIdx.y;   // 0..31  m-tile of 8
    const int b  = blockIdx.z;
    const int m0 = mt * 8;
    const int nbase = ns * 32;

    __shared__ __align__(16) ushort_t zhl[64 * 256];  // 32KB [row=m*8+n][256 swz]
    __shared__ float sc[2][8][8][9];                  // 4.6KB [buf][m][k][n+pad]
    __shared__ float t1[8][8][34];                    // 8.7KB [k][m][n(32)+pad]

    const int tid = threadIdx.x;
    const int lane = tid & 63, w = tid >> 6;
    const int fr = lane & 15, kg = lane >> 4;
    const int f8 = fr & 7;

    // ---- prologue: issue chunk-0 z loads (8 x float4 per thread)
    const int r_id = tid >> 2;            // 0..63 = zm*8 + zn
    const int zm = r_id >> 3, zn = r_id & 7;
    const int skey = zn ^ zm;
    const float* zrow_base = z + (((long)b * 256 + m0 + zm) * 256 + nbase + zn) * 128
                               + (tid & 3) * 32;
    float4 zr[8];
    #pragma unroll
    for (int i = 0; i < 8; i++) zr[i] = *(const float4*)(zrow_base + i * 4);

    // ---- t1 = xt.yt for this block (overlaps chunk-0 HBM latency)
    #pragma unroll
    for (int kk = 0; kk < 2; kk++) {
        const int k = w * 2 + kk;
        const long kb = (long)(b * 8 + k) * 256;
        #pragma unroll
        for (int nsub = 0; nsub < 2; nsub++) {
            f32x4 acc = {0.f, 0.f, 0.f, 0.f};
            #pragma unroll
            for (int s = 0; s < 2; s++) {
                short8 av = *(const short8*)(ytb + (kb + nbase + nsub * 16 + fr) * 64 + kg * 8 + s * 32);
                short8 bv = *(const short8*)(xtb + (kb + m0 + f8) * 64 + kg * 8 + s * 32);
                acc = MFMA16(av, bv, acc);
            }
            if (fr < 8) {
                #pragma unroll
                for (int j = 0; j < 4; j++)
                    t1[k][fr][nsub * 16 + kg * 4 + j] = acc[j];
            }
        }
    }
    __syncthreads();

    // ---- main loop over 4 chunks of 8 n
    for (int c = 0; c < 4; c++) {
        // stage chunk c from regs -> LDS (split once, swizzled, 2-way max)
        #pragma unroll
        for (int i = 0; i < 4; i++) {
            const int u = (i + (tid & 3)) & 3;
            short8 hi, lo;
            split8(zr[2 * u], zr[2 * u + 1], hi, lo);
            const int c16h = (tid & 3) * 4 + u;
            *(short8*)&zhl[r_id * 256 + phys16(c16h, skey) * 8] = hi;
            *(short8*)&zhl[r_id * 256 + phys16(c16h + 16, skey) * 8] = lo;
        }
        if (c < 3) {
            #pragma unroll
            for (int i = 0; i < 8; i++)
                zr[i] = *(const float4*)(zrow_base + (c + 1) * 1024 + i * 4);
        }
        __syncthreads();  // zhl(c) ready

        // phase2: termB. per m: D[row=n(kg<2), col=k(fr<8)], virtual-K 256.
        #pragma unroll
        for (int mi = 0; mi < 2; mi++) {
            const int m_loc = w * 2 + mi;
            const int keyr = f8 ^ m_loc;
            const int rowb = (m_loc * 8 + f8) * 256;
            const ushort_t* wp = wzyb + (((long)b * 256 + m0 + m_loc) * 8 + f8) * 128 + kg * 8;
            short8 wb[4], ah[4], al[4];
            #pragma unroll
            for (int s = 0; s < 4; s++) wb[s] = *(const short8*)(wp + s * 32);
            #pragma unroll
            for (int s = 0; s < 4; s++) {
                ah[s] = *(const short8*)&zhl[rowb + phys16(kg + 4 * s, keyr) * 8];
                al[s] = *(const short8*)&zhl[rowb + phys16(16 + kg + 4 * s, keyr) * 8];
            }
            f32x4 acc = {0.f, 0.f, 0.f, 0.f};
            #pragma unroll
            for (int s = 0; s < 4; s++) acc = MFMA16(ah[s], wb[s], acc);
            #pragma unroll
            for (int s = 0; s < 4; s++) acc = MFMA16(al[s], wb[s], acc);
            if (fr < 8 && kg < 2) {
                #pragma unroll
                for (int j = 0; j < 4; j++)
                    sc[c & 1][m_loc][fr][kg * 4 + j] = acc[j];
            }
        }
        __syncthreads();  // sc init complete

        // phase3: termC. per n: D[row=m(kg<2), col=k(fr<8)].
        #pragma unroll
        for (int ni = 0; ni < 2; ni++) {
            const int n_loc = w * 2 + ni;
            const int keyr = n_loc ^ f8;
            const int rowb = (f8 * 8 + n_loc) * 256;
            const ushort_t* wp = wzxb + (((long)b * 256 + nbase + c * 8 + n_loc) * 8 + f8) * 128 + kg * 8;
            short8 wb[4], ah[4], al[4];
            #pragma unroll
            for (int s = 0; s < 4; s++) wb[s] = *(const short8*)(wp + s * 32);
            #pragma unroll
            for (int s = 0; s < 4; s++) {
                ah[s] = *(const short8*)&zhl[rowb + phys16(kg + 4 * s, keyr) * 8];
                al[s] = *(const short8*)&zhl[rowb + phys16(16 + kg + 4 * s, keyr) * 8];
            }
            f32x4 acc = {0.f, 0.f, 0.f, 0.f};
            #pragma unroll
            for (int s = 0; s < 4; s++) acc = MFMA16(ah[s], wb[s], acc);
            #pragma unroll
            for (int s = 0; s < 4; s++) acc = MFMA16(al[s], wb[s], acc);
            if (fr < 8 && kg < 2) {
                #pragma unroll
                for (int j = 0; j < 4; j++)
                    sc[c & 1][kg * 4 + j][fr][n_loc] += acc[j];
            }
        }

        // epilogue for chunk c-1 (overlaps with other waves' phase3)
        if (c > 0 && lane < 16) {
            const int cp = c - 1;
            const int k = w * 2 + (lane >> 3);
            const int nl = lane & 7;
            const int nloc = cp * 8 + nl;
            float s8 = 0.f; ushort_t eb[8];
            #pragma unroll
            for (int m = 0; m < 8; m++) {
                const float e = exp2f((sc[cp & 1][m][k][nl] + t1[k][m][nloc]) * LOG2E_OVER_T);
                eb[m] = f2bf(e); s8 += e;
            }
            *(short8*)(Et + (((long)b * 8 + k) * 256 + nbase + nloc) * 256 + m0) = *(short8*)eb;
            atomicAdd(&ssum[(b * 8 + k) * 256 + nbase + nloc], s8);
        }
        __syncthreads();  // phase3 + epilogue done; zhl & sc reusable
    }

    // final epilogue (chunk 3)
    if (lane < 16) {
        const int k = w * 2 + (lane >> 3);
        const int nl = lane & 7;
        const int nloc = 3 * 8 + nl;
        float s8 = 0.f; ushort_t eb[8];
        #pragma unroll
        for (int m = 0; m < 8; m++) {
            const float e = exp2f((sc[1][m][k][nl] + t1[k][m][nloc]) * LOG2E_OVER_T);
            eb[m] = f2bf(e); s8 += e;
        }
        *(short8*)(Et + (((long)b * 8 + k) * 256 + nbase + nloc) * 256 + m0) = *(short8*)eb;
        atomicAdd(&ssum[(b * 8 + k) * 256 + nbase + nloc], s8);
    }
}

// ---------------------------------------------------------------------------
// ogemm: o2b[b][n][k*64+d] = bf16( (1/ssum[bk][n]) * sum_m Et[bk][n][m]*xvT[bk][d][m] )
// ---------------------------------------------------------------------------
__global__ __launch_bounds__(256)
void ogemm_kernel(const ushort_t* __restrict__ Et, const ushort_t* __restrict__ xvTb,
                  const float* __restrict__ ssum, ushort_t* __restrict__ o2b)
{
    const int mt = blockIdx.x, bk = blockIdx.y;
    f32x4 acc[2][2]; zero_acc(acc);
    mfma_core64(Et + ((long)bk * 256 + mt * 64) * 256, 256,
                xvTb + (long)bk * 64 * 256, 256, 8, acc);
    const int t = threadIdx.x, lane = t & 63, w = t >> 6;
    const int wr = w >> 1, wc = w & 1, fr = lane & 15, kg = lane >> 4;
    const int b = bk >> 3, k = bk & 7;
    #pragma unroll
    for (int mi = 0; mi < 2; mi++)
    #pragma unroll
    for (int j = 0; j < 4; j++) {
        const int n = mt * 64 + wr * 32 + mi * 16 + kg * 4 + j;
        const float inv = 1.0f / ssum[bk * 256 + n];
        #pragma unroll
        for (int ni = 0; ni < 2; ni++) {
            const int d = wc * 32 + ni * 16 + fr;
            o2b[((long)b * 256 + n) * 512 + k * 64 + d] = f2bf(acc[mi][ni][j] * inv);
        }
    }
}

// ---------------------------------------------------------------------------
// ygemm: out[b][n][q] = sum_kd o2b[b][n][kd] * TyTb[q][kd]   (fp32 out)
// ---------------------------------------------------------------------------
__global__ __launch_bounds__(256)
void ygemm_kernel(const ushort_t* __restrict__ o2b, const ushort_t* __restrict__ TyTb,
                  float* __restrict__ out)
{
    const int qt = blockIdx.x, mt = blockIdx.y, b = blockIdx.z;
    f32x4 acc[2][2]; zero_acc(acc);
    mfma_core64(o2b + ((long)b * 256 + mt * 64) * 512, 512,
                TyTb + (long)qt * 64 * 512, 512, 16, acc);
    const int t = threadIdx.x, lane = t & 63, w = t >> 6;
    const int wr = w >> 1, wc = w & 1, fr = lane & 15, kg = lane >> 4;
    #pragma unroll
    for (int mi = 0; mi < 2; mi++)
    #pragma unroll
    for (int ni = 0; ni < 2; ni++)
    #pragma unroll
    for (int j = 0; j < 4; j++) {
        const int n = mt * 64 + wr * 32 + mi * 16 + kg * 4 + j;
        const int q = qt * 64 + wc * 32 + ni * 16 + fr;
        out[((long)b * 256 + n) * 512 + q] = acc[mi][ni][j];
    }
}

// ---------------------------------------------------------------------------
extern "C" void kernel_launch(void* const* d_in, const int* in_sizes, int n_in,
                              void* d_out, int out_size, void* d_ws, size_t ws_size,
                              hipStream_t stream)
{
    const float* z       = (const float*)d_in[0];
    const float* y_q     = (const float*)d_in[1];
    const float* x_k     = (const float*)d_in[2];
    const float* Theta_x = (const float*)d_in[3];
    const float* Theta_y = (const float*)d_in[4];
    const float* Lam_x   = (const float*)d_in[5];
    const float* Lam_y   = (const float*)d_in[6];
    const float* Lam_zx  = (const float*)d_in[7];
    const float* Lam_zy  = (const float*)d_in[8];
    float* out = (float*)d_out;

    // --- workspace (ushort offsets, all disjoint, ~9.7 MiB total) ---
    ushort_t* U = (ushort_t*)d_ws;
    ushort_t* xkb  = U;               // 262144  [b][m][512]
    ushort_t* yqb  = U + 262144;      // 262144  [b][n][512]
    ushort_t* WxTb = U + 524288;      // 524288  [k][128dc][512p]
    ushort_t* WyTb = U + 1048576;     // 262144  [k][64d][512p]
    ushort_t* Zyb  = U + 1310720;     // 65536   [k][128r][64d]
    ushort_t* Zxb  = U + 1376256;     // 65536
    ushort_t* TyTb = U + 1441792;     // 262144  [q][k*64+d]
    ushort_t* xtb  = U + 1703936;     // 262144  [bk][m][64]
    ushort_t* ytb  = U + 1966080;     // 262144  [bk][n][64]
    ushort_t* xvTb = U + 2228224;     // 262144  [bk][64d][256m]
    ushort_t* wzyb = U + 2490368;     // 524288  [b][m][8k][128r]
    ushort_t* wzxb = U + 3014656;     // 524288  [b][n][8k][128r]
    ushort_t* Et   = U + 3538944;     // 1048576 [bk][n][256m]
    ushort_t* o2b  = U + 4587520;     // 262144  [b][n][512kd]
    float*    ssum = (float*)(U + 4849664);  // 4096 fp32 [bk][n]

    convert_kernel<<<6672, 256, 0, stream>>>(x_k, y_q, Lam_x, Theta_x, Lam_y,
        Lam_zy, Lam_zx, Theta_y, xkb, yqb, WxTb, WyTb, Zyb, Zxb, TyTb, ssum);

    proj_kernel<<<dim3(16, 8, 2), 256, 0, stream>>>(xkb, yqb, WxTb, WyTb,
        xtb, ytb, xvTb);

    step2_kernel<<<256, 256, 0, stream>>>(xtb, ytb, Zyb, Zxb, wzyb, wzxb);

    fused_score<<<dim3(8, 32, 2), 256, 0, stream>>>(z, xtb, ytb, wzyb, wzxb,
        Et, ssum);

    ogemm_kernel<<<dim3(4, 16), 256, 0, stream>>>(Et, xvTb, ssum, o2b);

    ygemm_kernel<<<dim3(8, 4, 2), 256, 0, stream>>>(o2b, TyTb, out);
}

// Round 6
// 71.259 us; speedup vs baseline: 1.1063x; 1.1063x over previous
//
#include <hip/hip_runtime.h>
#include <hip/hip_bf16.h>

// B=2, M=256, N=256, K=8, P=Q=Pp=Qp=512, D=Dp=64, R=128, TEMP=8
#define LOG2E_OVER_T 0.18033688011112042f  // log2(e)/8

typedef __attribute__((ext_vector_type(8))) short short8;
typedef __attribute__((ext_vector_type(4))) float f32x4;
typedef unsigned short ushort_t;
typedef unsigned long long ull_t;

#define MFMA16(a, b, c) __builtin_amdgcn_mfma_f32_16x16x32_bf16(a, b, c, 0, 0, 0)

__device__ __forceinline__ ushort_t f2bf(float f) {
    union { float f; unsigned u; } v; v.f = f;
    unsigned r = (v.u + 0x7fffu + ((v.u >> 16) & 1u)) >> 16;
    return (ushort_t)r;
}

// split 8 fp32 -> bf16 hi (truncate) + bf16 lo (residual, truncate).
__device__ __forceinline__ void split8(const float4 a, const float4 b,
                                       short8& hi, short8& lo)
{
    union { float f[8]; unsigned u[8]; } Z;
    Z.f[0] = a.x; Z.f[1] = a.y; Z.f[2] = a.z; Z.f[3] = a.w;
    Z.f[4] = b.x; Z.f[5] = b.y; Z.f[6] = b.z; Z.f[7] = b.w;
    union { unsigned u[4]; short8 s; } H, L;
    #pragma unroll
    for (int i = 0; i < 4; i++) {
        const unsigned u0 = Z.u[2 * i], u1 = Z.u[2 * i + 1];
        H.u[i] = __builtin_amdgcn_perm(u1, u0, 0x07060302u);  // [u0.hi16, u1.hi16]
        union { unsigned u; float f; } h0, h1;
        h0.u = u0 & 0xffff0000u; h1.u = u1 & 0xffff0000u;
        union { float f; unsigned u; } l0, l1;
        l0.f = Z.f[2 * i] - h0.f; l1.f = Z.f[2 * i + 1] - h1.f;
        L.u[i] = __builtin_amdgcn_perm(l1.u, l0.u, 0x07060302u);
    }
    hi = H.s; lo = L.s;
}

// ---------------------------------------------------------------------------
// MFMA core: C[64x64] = A[64xK] * Bt[64xK]^T, bf16 in, fp32 acc. (4 waves)
// ---------------------------------------------------------------------------
__device__ __forceinline__ void mfma_core64(
    const ushort_t* __restrict__ Ag, int lda,
    const ushort_t* __restrict__ Btg, int ldb,
    int ksteps, f32x4 acc[2][2])
{
    __shared__ __align__(16) ushort_t As[64 * 40];
    __shared__ __align__(16) ushort_t Bs[64 * 40];
    const int t = threadIdx.x;
    const int srow = t >> 2, skc = (t & 3) * 8;
    const int lane = t & 63, w = t >> 6;
    const int wr = w >> 1, wc = w & 1;
    const int fr = lane & 15, kg = lane >> 4;
    const int aoff = (wr * 32 + fr) * 40 + kg * 8;
    const int boff = (wc * 32 + fr) * 40 + kg * 8;
    const long arow = (long)srow * lda + skc;
    const long brow = (long)srow * ldb + skc;

    short8 ra = *(const short8*)(Ag + arow);
    short8 rb = *(const short8*)(Btg + brow);
    for (int kt = 0; kt < ksteps; kt++) {
        __syncthreads();
        *(short8*)&As[srow * 40 + skc] = ra;
        *(short8*)&Bs[srow * 40 + skc] = rb;
        __syncthreads();
        if (kt + 1 < ksteps) {
            ra = *(const short8*)(Ag + arow + (kt + 1) * 32);
            rb = *(const short8*)(Btg + brow + (kt + 1) * 32);
        }
        short8 a0 = *(const short8*)&As[aoff];
        short8 a1 = *(const short8*)&As[aoff + 16 * 40];
        short8 b0 = *(const short8*)&Bs[boff];
        short8 b1 = *(const short8*)&Bs[boff + 16 * 40];
        acc[0][0] = MFMA16(a0, b0, acc[0][0]);
        acc[0][1] = MFMA16(a0, b1, acc[0][1]);
        acc[1][0] = MFMA16(a1, b0, acc[1][0]);
        acc[1][1] = MFMA16(a1, b1, acc[1][1]);
    }
}

__device__ __forceinline__ void zero_acc(f32x4 acc[2][2]) {
    const f32x4 z4 = {0.f, 0.f, 0.f, 0.f};
    acc[0][0] = z4; acc[0][1] = z4; acc[1][0] = z4; acc[1][1] = z4;
}

// ---------------------------------------------------------------------------
// convert: fp32 -> bf16 casts + layout permutes; also zeroes ssum.
// ---------------------------------------------------------------------------
__global__ __launch_bounds__(256)
void convert_kernel(const float* __restrict__ x_k, const float* __restrict__ y_q,
                    const float* __restrict__ Lam_x, const float* __restrict__ Theta_x,
                    const float* __restrict__ Lam_y, const float* __restrict__ Lam_zy,
                    const float* __restrict__ Lam_zx, const float* __restrict__ Theta_y,
                    ushort_t* __restrict__ xkb, ushort_t* __restrict__ yqb,
                    ushort_t* __restrict__ WxTb, ushort_t* __restrict__ WyTb,
                    ushort_t* __restrict__ Zyb, ushort_t* __restrict__ Zxb,
                    ushort_t* __restrict__ TyTb, float* __restrict__ ssum)
{
    int i = blockIdx.x * 256 + threadIdx.x;
    if (i < 262144) { xkb[i] = f2bf(x_k[i]); return; }
    i -= 262144;
    if (i < 262144) { yqb[i] = f2bf(y_q[i]); return; }
    i -= 262144;
    if (i < 524288) {  // WxTb[k][dc][p] = (dc<64 ? Lam_x : Theta_x)[k][p][dc%64]
        const int k = i >> 16, rem = i & 65535, dc = rem >> 9, p = i & 511;
        const float v = (dc < 64) ? Lam_x[((long)k * 512 + p) * 64 + dc]
                                  : Theta_x[((long)k * 512 + p) * 64 + dc - 64];
        WxTb[i] = f2bf(v); return;
    }
    i -= 524288;
    if (i < 262144) {  // WyTb[k][d][p] = Lam_y[k][p][d]
        const int k = i >> 15, d = (i >> 9) & 63, p = i & 511;
        WyTb[i] = f2bf(Lam_y[((long)k * 512 + p) * 64 + d]); return;
    }
    i -= 262144;
    if (i < 65536) { Zyb[i] = f2bf(Lam_zy[i]); return; }
    i -= 65536;
    if (i < 65536) { Zxb[i] = f2bf(Lam_zx[i]); return; }
    i -= 65536;
    if (i < 262144) {  // TyTb[q][k*64+d] = Theta_y[k][q][d]
        const int q = i >> 9, kd = i & 511, k = kd >> 6, d = kd & 63;
        TyTb[i] = f2bf(Theta_y[((long)k * 512 + q) * 64 + d]); return;
    }
    i -= 262144;
    ssum[i] = 0.f;  // 4096 entries
}

// ---------------------------------------------------------------------------
// proj: side0: [b,m] x WxT -> xtb (bf16 [bk][m][64]) + xvT (bf16 [bk][64][m])
//       side1: [b,n] x WyT -> ytb (bf16 [bk][n][64])
// ---------------------------------------------------------------------------
__global__ __launch_bounds__(256)
void proj_kernel(const ushort_t* __restrict__ xkb, const ushort_t* __restrict__ yqb,
                 const ushort_t* __restrict__ WxTb, const ushort_t* __restrict__ WyTb,
                 ushort_t* __restrict__ xtb, ushort_t* __restrict__ ytb,
                 ushort_t* __restrict__ xvTb)
{
    const int side = blockIdx.z;
    const int bx = blockIdx.x, by = blockIdx.y;
    if (side == 1 && bx >= 8) return;
    f32x4 acc[2][2]; zero_acc(acc);
    const int t = threadIdx.x, lane = t & 63, w = t >> 6;
    const int wr = w >> 1, wc = w & 1, fr = lane & 15, kg = lane >> 4;

    if (side == 0) {
        mfma_core64(xkb + (long)(by * 64) * 512, 512,
                    WxTb + (long)(bx * 64) * 512, 512, 16, acc);
        const int k = bx >> 1, isxv = bx & 1;
        #pragma unroll
        for (int mi = 0; mi < 2; mi++)
        #pragma unroll
        for (int ni = 0; ni < 2; ni++) {
            const int grow0 = by * 64 + wr * 32 + mi * 16 + kg * 4;
            const int b = grow0 >> 8, m0 = grow0 & 255;
            const int d = wc * 32 + ni * 16 + fr;
            if (!isxv) {
                #pragma unroll
                for (int j = 0; j < 4; j++)
                    xtb[(((long)(b * 8 + k)) * 256 + m0 + j) * 64 + d] = f2bf(acc[mi][ni][j]);
            } else {
                ull_t pk = (ull_t)f2bf(acc[mi][ni][0])
                         | ((ull_t)f2bf(acc[mi][ni][1]) << 16)
                         | ((ull_t)f2bf(acc[mi][ni][2]) << 32)
                         | ((ull_t)f2bf(acc[mi][ni][3]) << 48);
                *(ull_t*)&xvTb[(((long)(b * 8 + k)) * 64 + d) * 256 + m0] = pk;
            }
        }
    } else {
        mfma_core64(yqb + (long)(by * 64) * 512, 512,
                    WyTb + (long)(bx * 64) * 512, 512, 16, acc);
        const int k = bx;
        #pragma unroll
        for (int mi = 0; mi < 2; mi++)
        #pragma unroll
        for (int ni = 0; ni < 2; ni++)
        #pragma unroll
        for (int j = 0; j < 4; j++) {
            const int grow = by * 64 + wr * 32 + mi * 16 + kg * 4 + j;
            const int b = grow >> 8, n = grow & 255;
            const int d = wc * 32 + ni * 16 + fr;
            ytb[(((long)(b * 8 + k)) * 256 + n) * 64 + d] = f2bf(acc[mi][ni][j]);
        }
    }
}

// ---------------------------------------------------------------------------
// step2: wzyb[b][m][k][128] = bf16(xt @ Lam_zy^T); wzxb[b][n][k][128] likewise.
// (k-minor layout so fused_score B-frags are 16B-contiguous per k-row)
// ---------------------------------------------------------------------------
__global__ __launch_bounds__(256)
void step2_kernel(const ushort_t* __restrict__ xtb, const ushort_t* __restrict__ ytb,
                  const ushort_t* __restrict__ Zyb, const ushort_t* __restrict__ Zxb,
                  ushort_t* __restrict__ wzyb, ushort_t* __restrict__ wzxb)
{
    const int bz = blockIdx.x;  // 256
    const int which = bz >> 7, idx = bz & 127;
    const int bk = idx >> 3, tile = idx & 7, mt = tile >> 1, nt = tile & 1;
    const int k = bk & 7, b = bk >> 3;
    const ushort_t* Ag  = (which ? ytb : xtb) + ((long)bk * 256 + mt * 64) * 64;
    const ushort_t* Btg = (which ? Zxb : Zyb) + ((long)k * 128 + nt * 64) * 64;
    ushort_t* C = which ? wzxb : wzyb;
    f32x4 acc[2][2]; zero_acc(acc);
    mfma_core64(Ag, 64, Btg, 64, 2, acc);
    const int t = threadIdx.x, lane = t & 63, w = t >> 6;
    const int wr = w >> 1, wc = w & 1, fr = lane & 15, kg = lane >> 4;
    #pragma unroll
    for (int mi = 0; mi < 2; mi++)
    #pragma unroll
    for (int ni = 0; ni < 2; ni++)
    #pragma unroll
    for (int j = 0; j < 4; j++) {
        const int m_glob = mt * 64 + wr * 32 + mi * 16 + kg * 4 + j;
        const int r_glob = nt * 64 + wc * 32 + ni * 16 + fr;
        C[(((long)b * 256 + m_glob) * 8 + k) * 128 + r_glob] = f2bf(acc[mi][ni][j]);
    }
}

// ---------------------------------------------------------------------------
// fused_score v3: block = 2 waves, tile 8m x 16n, waves split the r-dim.
// NO z staging, NO reg arrays, ONE barrier. Each wave:
//   p2 (termB, per m): A = z[m, 16n, r-half] split hi/lo, B = wzy[m][8k]
//   p3 (termC, per n): A = z[8m, n, r-half] split hi/lo, B = wzx[n][8k]
// Wave 0 additionally p1 (xt.yt). Partial scores in sc[w][8m][8k][16n].
// Epilogue: exp(sum/T) -> Et bf16 + ssum atomics.
// ---------------------------------------------------------------------------
__global__ __launch_bounds__(128)
void fused_score(const float* __restrict__ z,
                 const ushort_t* __restrict__ xtb, const ushort_t* __restrict__ ytb,
                 const ushort_t* __restrict__ wzyb, const ushort_t* __restrict__ wzxb,
                 ushort_t* __restrict__ Et, float* __restrict__ ssum)
{
    const int nt = blockIdx.x, mt = blockIdx.y, b = blockIdx.z;
    const int nbase = nt * 16, m0 = mt * 8;
    __shared__ float sc[2][8][8][17];  // [r-half][m][k][n+pad] = 8.7KB

    const int tid = threadIdx.x;
    const int lane = tid & 63, w = tid >> 6;   // w = r-half owner
    const int fr = lane & 15, kg = lane >> 4;
    const int f8 = fr & 7;
    const int rh = w * 64;

    if (w == 0) {
        // p1: xtyt -> sc[0][m][k][n]  (D[row=n, col=m])
        #pragma unroll 2
        for (int k = 0; k < 8; k++) {
            const long kb = (long)(b * 8 + k) * 256;
            short8 a0 = *(const short8*)(ytb + (kb + nbase + fr) * 64 + kg * 8);
            short8 b0 = *(const short8*)(xtb + (kb + m0 + f8) * 64 + kg * 8);
            short8 a1 = *(const short8*)(ytb + (kb + nbase + fr) * 64 + 32 + kg * 8);
            short8 b1 = *(const short8*)(xtb + (kb + m0 + f8) * 64 + 32 + kg * 8);
            f32x4 acc = {0.f, 0.f, 0.f, 0.f};
            acc = MFMA16(a0, b0, acc);
            acc = MFMA16(a1, b1, acc);
            if (fr < 8) {
                #pragma unroll
                for (int j = 0; j < 4; j++)
                    sc[0][fr][k][kg * 4 + j] = acc[j];
            }
        }
    }

    // p2: termB. per m: D[row=n, col=k]; wave0 '+=', wave1 '='
    #pragma unroll 2
    for (int m = 0; m < 8; m++) {
        const float* zp = z + (((long)b * 256 + m0 + m) * 256 + nbase + fr) * 128 + rh + kg * 8;
        const ushort_t* wp = wzyb + (((long)b * 256 + m0 + m) * 8 + f8) * 128 + rh + kg * 8;
        const float4 z00 = *(const float4*)(zp);
        const float4 z01 = *(const float4*)(zp + 4);
        const float4 z10 = *(const float4*)(zp + 32);
        const float4 z11 = *(const float4*)(zp + 36);
        const short8 w0 = *(const short8*)(wp);
        const short8 w1 = *(const short8*)(wp + 32);
        short8 h0, l0, h1, l1;
        split8(z00, z01, h0, l0);
        split8(z10, z11, h1, l1);
        f32x4 acc = {0.f, 0.f, 0.f, 0.f};
        acc = MFMA16(h0, w0, acc);
        acc = MFMA16(h1, w1, acc);
        acc = MFMA16(l0, w0, acc);
        acc = MFMA16(l1, w1, acc);
        if (fr < 8) {
            if (w == 0) {
                #pragma unroll
                for (int j = 0; j < 4; j++)
                    sc[0][m][fr][kg * 4 + j] += acc[j];
            } else {
                #pragma unroll
                for (int j = 0; j < 4; j++)
                    sc[1][m][fr][kg * 4 + j] = acc[j];
            }
        }
    }

    // p3: termC. per n: D[row=m(<8), col=k]; '+=' for both waves
    #pragma unroll 2
    for (int n = 0; n < 16; n++) {
        const float* zp = z + (((long)b * 256 + m0 + f8) * 256 + nbase + n) * 128 + rh + kg * 8;
        const ushort_t* wp = wzxb + (((long)b * 256 + nbase + n) * 8 + f8) * 128 + rh + kg * 8;
        const float4 z00 = *(const float4*)(zp);
        const float4 z01 = *(const float4*)(zp + 4);
        const float4 z10 = *(const float4*)(zp + 32);
        const float4 z11 = *(const float4*)(zp + 36);
        const short8 w0 = *(const short8*)(wp);
        const short8 w1 = *(const short8*)(wp + 32);
        short8 h0, l0, h1, l1;
        split8(z00, z01, h0, l0);
        split8(z10, z11, h1, l1);
        f32x4 acc = {0.f, 0.f, 0.f, 0.f};
        acc = MFMA16(h0, w0, acc);
        acc = MFMA16(h1, w1, acc);
        acc = MFMA16(l0, w0, acc);
        acc = MFMA16(l1, w1, acc);
        if (fr < 8 && kg < 2) {
            #pragma unroll
            for (int j = 0; j < 4; j++)
                sc[w][kg * 4 + j][fr][n] += acc[j];
        }
    }
    __syncthreads();

    // epilogue: 128 threads, one (k,n) each: exp -> Et + ssum atomic
    {
        const int k = tid >> 4, n = tid & 15;
        float s8 = 0.f;
        ushort_t eb[8];
        #pragma unroll
        for (int m = 0; m < 8; m++) {
            const float e = exp2f((sc[0][m][k][n] + sc[1][m][k][n]) * LOG2E_OVER_T);
            eb[m] = f2bf(e);
            s8 += e;
        }
        *(short8*)(Et + (((long)b * 8 + k) * 256 + nbase + n) * 256 + m0) = *(short8*)eb;
        atomicAdd(&ssum[(b * 8 + k) * 256 + nbase + n], s8);
    }
}

// ---------------------------------------------------------------------------
// ogemm: o2b[b][n][k*64+d] = bf16( (1/ssum[bk][n]) * sum_m Et[bk][n][m]*xvT[bk][d][m] )
// ---------------------------------------------------------------------------
__global__ __launch_bounds__(256)
void ogemm_kernel(const ushort_t* __restrict__ Et, const ushort_t* __restrict__ xvTb,
                  const float* __restrict__ ssum, ushort_t* __restrict__ o2b)
{
    const int mt = blockIdx.x, bk = blockIdx.y;
    f32x4 acc[2][2]; zero_acc(acc);
    mfma_core64(Et + ((long)bk * 256 + mt * 64) * 256, 256,
                xvTb + (long)bk * 64 * 256, 256, 8, acc);
    const int t = threadIdx.x, lane = t & 63, w = t >> 6;
    const int wr = w >> 1, wc = w & 1, fr = lane & 15, kg = lane >> 4;
    const int b = bk >> 3, k = bk & 7;
    #pragma unroll
    for (int mi = 0; mi < 2; mi++)
    #pragma unroll
    for (int j = 0; j < 4; j++) {
        const int n = mt * 64 + wr * 32 + mi * 16 + kg * 4 + j;
        const float inv = 1.0f / ssum[bk * 256 + n];
        #pragma unroll
        for (int ni = 0; ni < 2; ni++) {
            const int d = wc * 32 + ni * 16 + fr;
            o2b[((long)b * 256 + n) * 512 + k * 64 + d] = f2bf(acc[mi][ni][j] * inv);
        }
    }
}

// ---------------------------------------------------------------------------
// ygemm: out[b][n][q] = sum_kd o2b[b][n][kd] * TyTb[q][kd]   (fp32 out)
// ---------------------------------------------------------------------------
__global__ __launch_bounds__(256)
void ygemm_kernel(const ushort_t* __restrict__ o2b, const ushort_t* __restrict__ TyTb,
                  float* __restrict__ out)
{
    const int qt = blockIdx.x, mt = blockIdx.y, b = blockIdx.z;
    f32x4 acc[2][2]; zero_acc(acc);
    mfma_core64(o2b + ((long)b * 256 + mt * 64) * 512, 512,
                TyTb + (long)qt * 64 * 512, 512, 16, acc);
    const int t = threadIdx.x, lane = t & 63, w = t >> 6;
    const int wr = w >> 1, wc = w & 1, fr = lane & 15, kg = lane >> 4;
    #pragma unroll
    for (int mi = 0; mi < 2; mi++)
    #pragma unroll
    for (int ni = 0; ni < 2; ni++)
    #pragma unroll
    for (int j = 0; j < 4; j++) {
        const int n = mt * 64 + wr * 32 + mi * 16 + kg * 4 + j;
        const int q = qt * 64 + wc * 32 + ni * 16 + fr;
        out[((long)b * 256 + n) * 512 + q] = acc[mi][ni][j];
    }
}

// ---------------------------------------------------------------------------
extern "C" void kernel_launch(void* const* d_in, const int* in_sizes, int n_in,
                              void* d_out, int out_size, void* d_ws, size_t ws_size,
                              hipStream_t stream)
{
    const float* z       = (const float*)d_in[0];
    const float* y_q     = (const float*)d_in[1];
    const float* x_k     = (const float*)d_in[2];
    const float* Theta_x = (const float*)d_in[3];
    const float* Theta_y = (const float*)d_in[4];
    const float* Lam_x   = (const float*)d_in[5];
    const float* Lam_y   = (const float*)d_in[6];
    const float* Lam_zx  = (const float*)d_in[7];
    const float* Lam_zy  = (const float*)d_in[8];
    float* out = (float*)d_out;

    // --- workspace (ushort offsets, all disjoint, ~9.7 MiB total) ---
    ushort_t* U = (ushort_t*)d_ws;
    ushort_t* xkb  = U;               // 262144  [b][m][512]
    ushort_t* yqb  = U + 262144;      // 262144  [b][n][512]
    ushort_t* WxTb = U + 524288;      // 524288  [k][128dc][512p]
    ushort_t* WyTb = U + 1048576;     // 262144  [k][64d][512p]
    ushort_t* Zyb  = U + 1310720;     // 65536   [k][128r][64d]
    ushort_t* Zxb  = U + 1376256;     // 65536
    ushort_t* TyTb = U + 1441792;     // 262144  [q][k*64+d]
    ushort_t* xtb  = U + 1703936;     // 262144  [bk][m][64]
    ushort_t* ytb  = U + 1966080;     // 262144  [bk][n][64]
    ushort_t* xvTb = U + 2228224;     // 262144  [bk][64d][256m]
    ushort_t* wzyb = U + 2490368;     // 524288  [b][m][8k][128r]
    ushort_t* wzxb = U + 3014656;     // 524288  [b][n][8k][128r]
    ushort_t* Et   = U + 3538944;     // 1048576 [bk][n][256m]
    ushort_t* o2b  = U + 4587520;     // 262144  [b][n][512kd]
    float*    ssum = (float*)(U + 4849664);  // 4096 fp32 [bk][n]

    convert_kernel<<<6672, 256, 0, stream>>>(x_k, y_q, Lam_x, Theta_x, Lam_y,
        Lam_zy, Lam_zx, Theta_y, xkb, yqb, WxTb, WyTb, Zyb, Zxb, TyTb, ssum);

    proj_kernel<<<dim3(16, 8, 2), 256, 0, stream>>>(xkb, yqb, WxTb, WyTb,
        xtb, ytb, xvTb);

    step2_kernel<<<256, 256, 0, stream>>>(xtb, ytb, Zyb, Zxb, wzyb, wzxb);

    fused_score<<<dim3(16, 32, 2), 128, 0, stream>>>(z, xtb, ytb, wzyb, wzxb,
        Et, ssum);

    ogemm_kernel<<<dim3(4, 16), 256, 0, stream>>>(Et, xvTb, ssum, o2b);

    ygemm_kernel<<<dim3(8, 4, 2), 256, 0, stream>>>(o2b, TyTb, out);
}

// Round 7
// 70.003 us; speedup vs baseline: 1.1262x; 1.0179x over previous
//
#include <hip/hip_runtime.h>
#include <hip/hip_bf16.h>

// B=2, M=256, N=256, K=8, P=Q=Pp=Qp=512, D=Dp=64, R=128, TEMP=8
#define LOG2E_OVER_T 0.18033688011112042f  // log2(e)/8

typedef __attribute__((ext_vector_type(8))) short short8;
typedef __attribute__((ext_vector_type(4))) float f32x4;
typedef unsigned short ushort_t;
typedef unsigned long long ull_t;

#define MFMA16(a, b, c) __builtin_amdgcn_mfma_f32_16x16x32_bf16(a, b, c, 0, 0, 0)

__device__ __forceinline__ ushort_t f2bf(float f) {
    union { float f; unsigned u; } v; v.f = f;
    unsigned r = (v.u + 0x7fffu + ((v.u >> 16) & 1u)) >> 16;
    return (ushort_t)r;
}

// split 8 fp32 -> bf16 hi (truncate) + bf16 lo (residual, truncate).
__device__ __forceinline__ void split8(const float4 a, const float4 b,
                                       short8& hi, short8& lo)
{
    union { float f[8]; unsigned u[8]; } Z;
    Z.f[0] = a.x; Z.f[1] = a.y; Z.f[2] = a.z; Z.f[3] = a.w;
    Z.f[4] = b.x; Z.f[5] = b.y; Z.f[6] = b.z; Z.f[7] = b.w;
    union { unsigned u[4]; short8 s; } H, L;
    #pragma unroll
    for (int i = 0; i < 4; i++) {
        const unsigned u0 = Z.u[2 * i], u1 = Z.u[2 * i + 1];
        H.u[i] = __builtin_amdgcn_perm(u1, u0, 0x07060302u);  // [u0.hi16, u1.hi16]
        union { unsigned u; float f; } h0, h1;
        h0.u = u0 & 0xffff0000u; h1.u = u1 & 0xffff0000u;
        union { float f; unsigned u; } l0, l1;
        l0.f = Z.f[2 * i] - h0.f; l1.f = Z.f[2 * i + 1] - h1.f;
        L.u[i] = __builtin_amdgcn_perm(l1.u, l0.u, 0x07060302u);
    }
    hi = H.s; lo = L.s;
}

// ---------------------------------------------------------------------------
// MFMA core: C[64x64] = A[64xK] * Bt[64xK]^T, bf16 in, fp32 acc. (4 waves)
// ---------------------------------------------------------------------------
__device__ __forceinline__ void mfma_core64(
    const ushort_t* __restrict__ Ag, int lda,
    const ushort_t* __restrict__ Btg, int ldb,
    int ksteps, f32x4 acc[2][2])
{
    __shared__ __align__(16) ushort_t As[64 * 40];
    __shared__ __align__(16) ushort_t Bs[64 * 40];
    const int t = threadIdx.x;
    const int srow = t >> 2, skc = (t & 3) * 8;
    const int lane = t & 63, w = t >> 6;
    const int wr = w >> 1, wc = w & 1;
    const int fr = lane & 15, kg = lane >> 4;
    const int aoff = (wr * 32 + fr) * 40 + kg * 8;
    const int boff = (wc * 32 + fr) * 40 + kg * 8;
    const long arow = (long)srow * lda + skc;
    const long brow = (long)srow * ldb + skc;

    short8 ra = *(const short8*)(Ag + arow);
    short8 rb = *(const short8*)(Btg + brow);
    for (int kt = 0; kt < ksteps; kt++) {
        __syncthreads();
        *(short8*)&As[srow * 40 + skc] = ra;
        *(short8*)&Bs[srow * 40 + skc] = rb;
        __syncthreads();
        if (kt + 1 < ksteps) {
            ra = *(const short8*)(Ag + arow + (kt + 1) * 32);
            rb = *(const short8*)(Btg + brow + (kt + 1) * 32);
        }
        short8 a0 = *(const short8*)&As[aoff];
        short8 a1 = *(const short8*)&As[aoff + 16 * 40];
        short8 b0 = *(const short8*)&Bs[boff];
        short8 b1 = *(const short8*)&Bs[boff + 16 * 40];
        acc[0][0] = MFMA16(a0, b0, acc[0][0]);
        acc[0][1] = MFMA16(a0, b1, acc[0][1]);
        acc[1][0] = MFMA16(a1, b0, acc[1][0]);
        acc[1][1] = MFMA16(a1, b1, acc[1][1]);
    }
}

__device__ __forceinline__ void zero_acc(f32x4 acc[2][2]) {
    const f32x4 z4 = {0.f, 0.f, 0.f, 0.f};
    acc[0][0] = z4; acc[0][1] = z4; acc[1][0] = z4; acc[1][1] = z4;
}

// ---------------------------------------------------------------------------
// convert: fp32 -> bf16 casts + layout permutes; also zeroes ssum.
// ---------------------------------------------------------------------------
__global__ __launch_bounds__(256)
void convert_kernel(const float* __restrict__ x_k, const float* __restrict__ y_q,
                    const float* __restrict__ Lam_x, const float* __restrict__ Theta_x,
                    const float* __restrict__ Lam_y, const float* __restrict__ Lam_zy,
                    const float* __restrict__ Lam_zx, const float* __restrict__ Theta_y,
                    ushort_t* __restrict__ xkb, ushort_t* __restrict__ yqb,
                    ushort_t* __restrict__ WxTb, ushort_t* __restrict__ WyTb,
                    ushort_t* __restrict__ Zyb, ushort_t* __restrict__ Zxb,
                    ushort_t* __restrict__ TyTb, float* __restrict__ ssum)
{
    int i = blockIdx.x * 256 + threadIdx.x;
    if (i < 262144) { xkb[i] = f2bf(x_k[i]); return; }
    i -= 262144;
    if (i < 262144) { yqb[i] = f2bf(y_q[i]); return; }
    i -= 262144;
    if (i < 524288) {  // WxTb[k][dc][p] = (dc<64 ? Lam_x : Theta_x)[k][p][dc%64]
        const int k = i >> 16, rem = i & 65535, dc = rem >> 9, p = i & 511;
        const float v = (dc < 64) ? Lam_x[((long)k * 512 + p) * 64 + dc]
                                  : Theta_x[((long)k * 512 + p) * 64 + dc - 64];
        WxTb[i] = f2bf(v); return;
    }
    i -= 524288;
    if (i < 262144) {  // WyTb[k][d][p] = Lam_y[k][p][d]
        const int k = i >> 15, d = (i >> 9) & 63, p = i & 511;
        WyTb[i] = f2bf(Lam_y[((long)k * 512 + p) * 64 + d]); return;
    }
    i -= 262144;
    if (i < 65536) { Zyb[i] = f2bf(Lam_zy[i]); return; }
    i -= 65536;
    if (i < 65536) { Zxb[i] = f2bf(Lam_zx[i]); return; }
    i -= 65536;
    if (i < 262144) {  // TyTb[q][k*64+d] = Theta_y[k][q][d]
        const int q = i >> 9, kd = i & 511, k = kd >> 6, d = kd & 63;
        TyTb[i] = f2bf(Theta_y[((long)k * 512 + q) * 64 + d]); return;
    }
    i -= 262144;
    ssum[i] = 0.f;  // 4096 entries
}

// ---------------------------------------------------------------------------
// proj: side0: [b,m] x WxT -> xtb (bf16 [bk][m][64]) + xvT (bf16 [bk][64][m])
//       side1: [b,n] x WyT -> ytb (bf16 [bk][n][64])
// ---------------------------------------------------------------------------
__global__ __launch_bounds__(256)
void proj_kernel(const ushort_t* __restrict__ xkb, const ushort_t* __restrict__ yqb,
                 const ushort_t* __restrict__ WxTb, const ushort_t* __restrict__ WyTb,
                 ushort_t* __restrict__ xtb, ushort_t* __restrict__ ytb,
                 ushort_t* __restrict__ xvTb)
{
    const int side = blockIdx.z;
    const int bx = blockIdx.x, by = blockIdx.y;
    if (side == 1 && bx >= 8) return;
    f32x4 acc[2][2]; zero_acc(acc);
    const int t = threadIdx.x, lane = t & 63, w = t >> 6;
    const int wr = w >> 1, wc = w & 1, fr = lane & 15, kg = lane >> 4;

    if (side == 0) {
        mfma_core64(xkb + (long)(by * 64) * 512, 512,
                    WxTb + (long)(bx * 64) * 512, 512, 16, acc);
        const int k = bx >> 1, isxv = bx & 1;
        #pragma unroll
        for (int mi = 0; mi < 2; mi++)
        #pragma unroll
        for (int ni = 0; ni < 2; ni++) {
            const int grow0 = by * 64 + wr * 32 + mi * 16 + kg * 4;
            const int b = grow0 >> 8, m0 = grow0 & 255;
            const int d = wc * 32 + ni * 16 + fr;
            if (!isxv) {
                #pragma unroll
                for (int j = 0; j < 4; j++)
                    xtb[(((long)(b * 8 + k)) * 256 + m0 + j) * 64 + d] = f2bf(acc[mi][ni][j]);
            } else {
                ull_t pk = (ull_t)f2bf(acc[mi][ni][0])
                         | ((ull_t)f2bf(acc[mi][ni][1]) << 16)
                         | ((ull_t)f2bf(acc[mi][ni][2]) << 32)
                         | ((ull_t)f2bf(acc[mi][ni][3]) << 48);
                *(ull_t*)&xvTb[(((long)(b * 8 + k)) * 64 + d) * 256 + m0] = pk;
            }
        }
    } else {
        mfma_core64(yqb + (long)(by * 64) * 512, 512,
                    WyTb + (long)(bx * 64) * 512, 512, 16, acc);
        const int k = bx;
        #pragma unroll
        for (int mi = 0; mi < 2; mi++)
        #pragma unroll
        for (int ni = 0; ni < 2; ni++)
        #pragma unroll
        for (int j = 0; j < 4; j++) {
            const int grow = by * 64 + wr * 32 + mi * 16 + kg * 4 + j;
            const int b = grow >> 8, n = grow & 255;
            const int d = wc * 32 + ni * 16 + fr;
            ytb[(((long)(b * 8 + k)) * 256 + n) * 64 + d] = f2bf(acc[mi][ni][j]);
        }
    }
}

// ---------------------------------------------------------------------------
// step2: bz<256:  wzyb[b][m][k][128] = bf16(xt @ Lam_zy^T), wzxb likewise.
//        bz>=256: t1[bk][n][m] = fp32(yt @ xt^T)  (xt.yt scores, transposed)
// ---------------------------------------------------------------------------
__global__ __launch_bounds__(256)
void step2_kernel(const ushort_t* __restrict__ xtb, const ushort_t* __restrict__ ytb,
                  const ushort_t* __restrict__ Zyb, const ushort_t* __restrict__ Zxb,
                  ushort_t* __restrict__ wzyb, ushort_t* __restrict__ wzxb,
                  float* __restrict__ t1)
{
    const int bz = blockIdx.x;  // 512
    const int t = threadIdx.x, lane = t & 63, w = t >> 6;
    const int wr = w >> 1, wc = w & 1, fr = lane & 15, kg = lane >> 4;

    if (bz < 256) {
        const int which = bz >> 7, idx = bz & 127;
        const int bk = idx >> 3, tile = idx & 7, mt = tile >> 1, nt = tile & 1;
        const int k = bk & 7, b = bk >> 3;
        const ushort_t* Ag  = (which ? ytb : xtb) + ((long)bk * 256 + mt * 64) * 64;
        const ushort_t* Btg = (which ? Zxb : Zyb) + ((long)k * 128 + nt * 64) * 64;
        ushort_t* C = which ? wzxb : wzyb;
        f32x4 acc[2][2]; zero_acc(acc);
        mfma_core64(Ag, 64, Btg, 64, 2, acc);
        #pragma unroll
        for (int mi = 0; mi < 2; mi++)
        #pragma unroll
        for (int ni = 0; ni < 2; ni++)
        #pragma unroll
        for (int j = 0; j < 4; j++) {
            const int m_glob = mt * 64 + wr * 32 + mi * 16 + kg * 4 + j;
            const int r_glob = nt * 64 + wc * 32 + ni * 16 + fr;
            C[(((long)b * 256 + m_glob) * 8 + k) * 128 + r_glob] = f2bf(acc[mi][ni][j]);
        }
    } else {
        const int idx = bz - 256;
        const int bk = idx >> 4, tile = idx & 15, nt2 = tile >> 2, mt2 = tile & 3;
        f32x4 acc[2][2]; zero_acc(acc);
        mfma_core64(ytb + ((long)bk * 256 + nt2 * 64) * 64, 64,
                    xtb + ((long)bk * 256 + mt2 * 64) * 64, 64, 2, acc);
        #pragma unroll
        for (int mi = 0; mi < 2; mi++)
        #pragma unroll
        for (int ni = 0; ni < 2; ni++)
        #pragma unroll
        for (int j = 0; j < 4; j++) {
            const int n_glob = nt2 * 64 + wr * 32 + mi * 16 + kg * 4 + j;
            const int m_glob = mt2 * 64 + wc * 32 + ni * 16 + fr;
            t1[((long)bk * 256 + n_glob) * 256 + m_glob] = acc[mi][ni][j];
        }
    }
}

// ---------------------------------------------------------------------------
// fused_score v4: block = 4 waves (r-quarters), tile 8m x 16n. No z staging,
// explicit 2-deep register prefetch, one barrier. Per wave:
//   p2 (termB, per m): A = z[m, 16n, 32r] hi/lo, B = wzy[m][8k][32r]
//   p3 (termC, per n): A = z[8m, n, 32r] hi/lo, B = wzx[n][8k][32r]
// Partials in sc[4][m][k][n]; epilogue adds t1 (xt.yt), exp -> Et + ssum.
// ---------------------------------------------------------------------------
__global__ __launch_bounds__(256)
void fused_score(const float* __restrict__ z,
                 const ushort_t* __restrict__ wzyb, const ushort_t* __restrict__ wzxb,
                 const float* __restrict__ t1, ushort_t* __restrict__ Et,
                 float* __restrict__ ssum)
{
    const int nt = blockIdx.x, mt = blockIdx.y, b = blockIdx.z;
    const int nbase = nt * 16, m0 = mt * 8;
    __shared__ float sc[4][8][8][17];  // 17.4 KB [r-quarter][m][k][n+pad]

    const int tid = threadIdx.x;
    const int lane = tid & 63, w = tid >> 6;   // w = r-quarter
    const int fr = lane & 15, kg = lane >> 4;
    const int f8 = fr & 7;
    const int rh = w * 32;

    // ---- p2: termB. per m: D[row=n(kg*4+j), col=k(fr<8)]
    {
        const float* zp = z + (((long)b * 256 + m0) * 256 + nbase + fr) * 128 + rh + kg * 8;
        const ushort_t* wp = wzyb + (((long)b * 256 + m0) * 8 + f8) * 128 + rh + kg * 8;
        float4 za = *(const float4*)(zp);
        float4 zb = *(const float4*)(zp + 4);
        short8 wa = *(const short8*)(wp);
        float4 zc = *(const float4*)(zp + 32768);
        float4 zd = *(const float4*)(zp + 32768 + 4);
        short8 wb = *(const short8*)(wp + 1024);
        #pragma unroll
        for (int m = 0; m < 8; m++) {
            const int mnx = (m + 2 < 8) ? m + 2 : m;
            float4 ze = *(const float4*)(zp + mnx * 32768);
            float4 zf = *(const float4*)(zp + mnx * 32768 + 4);
            short8 wc = *(const short8*)(wp + mnx * 1024);
            short8 hi, lo;
            split8(za, zb, hi, lo);
            f32x4 acc = {0.f, 0.f, 0.f, 0.f};
            acc = MFMA16(hi, wa, acc);
            acc = MFMA16(lo, wa, acc);
            if (fr < 8) {
                #pragma unroll
                for (int j = 0; j < 4; j++)
                    sc[w][m][fr][kg * 4 + j] = acc[j];
            }
            za = zc; zb = zd; wa = wb;
            zc = ze; zd = zf; wb = wc;
        }
    }

    // ---- p3: termC. per n: D[row=m(kg<2), col=k(fr<8)]
    {
        const float* zp = z + (((long)b * 256 + m0 + f8) * 256 + nbase) * 128 + rh + kg * 8;
        const ushort_t* wp = wzxb + (((long)b * 256 + nbase) * 8 + f8) * 128 + rh + kg * 8;
        float4 za = *(const float4*)(zp);
        float4 zb = *(const float4*)(zp + 4);
        short8 wa = *(const short8*)(wp);
        float4 zc = *(const float4*)(zp + 128);
        float4 zd = *(const float4*)(zp + 128 + 4);
        short8 wb = *(const short8*)(wp + 1024);
        #pragma unroll
        for (int n = 0; n < 16; n++) {
            const int nnx = (n + 2 < 16) ? n + 2 : n;
            float4 ze = *(const float4*)(zp + nnx * 128);
            float4 zf = *(const float4*)(zp + nnx * 128 + 4);
            short8 wc = *(const short8*)(wp + nnx * 1024);
            short8 hi, lo;
            split8(za, zb, hi, lo);
            f32x4 acc = {0.f, 0.f, 0.f, 0.f};
            acc = MFMA16(hi, wa, acc);
            acc = MFMA16(lo, wa, acc);
            if (fr < 8 && kg < 2) {
                #pragma unroll
                for (int j = 0; j < 4; j++)
                    sc[w][kg * 4 + j][fr][n] += acc[j];
            }
            za = zc; zb = zd; wa = wb;
            zc = ze; zd = zf; wb = wc;
        }
    }
    __syncthreads();

    // ---- epilogue: 128 threads, one (k,n) each: sum quarters + t1, exp
    if (tid < 128) {
        const int k = tid >> 4, n = tid & 15;
        const float* tp = t1 + (((long)b * 8 + k) * 256 + nbase + n) * 256 + m0;
        const float4 t0 = *(const float4*)(tp);
        const float4 t4 = *(const float4*)(tp + 4);
        const float tv[8] = {t0.x, t0.y, t0.z, t0.w, t4.x, t4.y, t4.z, t4.w};
        float s8 = 0.f;
        ushort_t eb[8];
        #pragma unroll
        for (int m = 0; m < 8; m++) {
            const float s = sc[0][m][k][n] + sc[1][m][k][n]
                          + sc[2][m][k][n] + sc[3][m][k][n] + tv[m];
            const float e = exp2f(s * LOG2E_OVER_T);
            eb[m] = f2bf(e);
            s8 += e;
        }
        *(short8*)(Et + (((long)b * 8 + k) * 256 + nbase + n) * 256 + m0) = *(short8*)eb;
        atomicAdd(&ssum[(b * 8 + k) * 256 + nbase + n], s8);
    }
}

// ---------------------------------------------------------------------------
// ogemm: o2b[b][n][k*64+d] = bf16( (1/ssum[bk][n]) * sum_m Et[bk][n][m]*xvT[bk][d][m] )
// ---------------------------------------------------------------------------
__global__ __launch_bounds__(256)
void ogemm_kernel(const ushort_t* __restrict__ Et, const ushort_t* __restrict__ xvTb,
                  const float* __restrict__ ssum, ushort_t* __restrict__ o2b)
{
    const int mt = blockIdx.x, bk = blockIdx.y;
    f32x4 acc[2][2]; zero_acc(acc);
    mfma_core64(Et + ((long)bk * 256 + mt * 64) * 256, 256,
                xvTb + (long)bk * 64 * 256, 256, 8, acc);
    const int t = threadIdx.x, lane = t & 63, w = t >> 6;
    const int wr = w >> 1, wc = w & 1, fr = lane & 15, kg = lane >> 4;
    const int b = bk >> 3, k = bk & 7;
    #pragma unroll
    for (int mi = 0; mi < 2; mi++)
    #pragma unroll
    for (int j = 0; j < 4; j++) {
        const int n = mt * 64 + wr * 32 + mi * 16 + kg * 4 + j;
        const float inv = 1.0f / ssum[bk * 256 + n];
        #pragma unroll
        for (int ni = 0; ni < 2; ni++) {
            const int d = wc * 32 + ni * 16 + fr;
            o2b[((long)b * 256 + n) * 512 + k * 64 + d] = f2bf(acc[mi][ni][j] * inv);
        }
    }
}

// ---------------------------------------------------------------------------
// ygemm: out[b][n][q] = sum_kd o2b[b][n][kd] * TyTb[q][kd]   (fp32 out)
// ---------------------------------------------------------------------------
__global__ __launch_bounds__(256)
void ygemm_kernel(const ushort_t* __restrict__ o2b, const ushort_t* __restrict__ TyTb,
                  float* __restrict__ out)
{
    const int qt = blockIdx.x, mt = blockIdx.y, b = blockIdx.z;
    f32x4 acc[2][2]; zero_acc(acc);
    mfma_core64(o2b + ((long)b * 256 + mt * 64) * 512, 512,
                TyTb + (long)qt * 64 * 512, 512, 16, acc);
    const int t = threadIdx.x, lane = t & 63, w = t >> 6;
    const int wr = w >> 1, wc = w & 1, fr = lane & 15, kg = lane >> 4;
    #pragma unroll
    for (int mi = 0; mi < 2; mi++)
    #pragma unroll
    for (int ni = 0; ni < 2; ni++)
    #pragma unroll
    for (int j = 0; j < 4; j++) {
        const int n = mt * 64 + wr * 32 + mi * 16 + kg * 4 + j;
        const int q = qt * 64 + wc * 32 + ni * 16 + fr;
        out[((long)b * 256 + n) * 512 + q] = acc[mi][ni][j];
    }
}

// ---------------------------------------------------------------------------
extern "C" void kernel_launch(void* const* d_in, const int* in_sizes, int n_in,
                              void* d_out, int out_size, void* d_ws, size_t ws_size,
                              hipStream_t stream)
{
    const float* z       = (const float*)d_in[0];
    const float* y_q     = (const float*)d_in[1];
    const float* x_k     = (const float*)d_in[2];
    const float* Theta_x = (const float*)d_in[3];
    const float* Theta_y = (const float*)d_in[4];
    const float* Lam_x   = (const float*)d_in[5];
    const float* Lam_y   = (const float*)d_in[6];
    const float* Lam_zx  = (const float*)d_in[7];
    const float* Lam_zy  = (const float*)d_in[8];
    float* out = (float*)d_out;

    // --- workspace (ushort offsets, all disjoint, ~13.9 MiB total) ---
    ushort_t* U = (ushort_t*)d_ws;
    ushort_t* xkb  = U;               // 262144  [b][m][512]
    ushort_t* yqb  = U + 262144;      // 262144  [b][n][512]
    ushort_t* WxTb = U + 524288;      // 524288  [k][128dc][512p]
    ushort_t* WyTb = U + 1048576;     // 262144  [k][64d][512p]
    ushort_t* Zyb  = U + 1310720;     // 65536   [k][128r][64d]
    ushort_t* Zxb  = U + 1376256;     // 65536
    ushort_t* TyTb = U + 1441792;     // 262144  [q][k*64+d]
    ushort_t* xtb  = U + 1703936;     // 262144  [bk][m][64]
    ushort_t* ytb  = U + 1966080;     // 262144  [bk][n][64]
    ushort_t* xvTb = U + 2228224;     // 262144  [bk][64d][256m]
    ushort_t* wzyb = U + 2490368;     // 524288  [b][m][8k][128r]
    ushort_t* wzxb = U + 3014656;     // 524288  [b][n][8k][128r]
    ushort_t* Et   = U + 3538944;     // 1048576 [bk][n][256m]
    ushort_t* o2b  = U + 4587520;     // 262144  [b][n][512kd]
    float*    ssum = (float*)(U + 4849664);  // 4096 fp32 [bk][n]
    float*    t1   = (float*)(U + 4857856);  // 1048576 fp32 [bk][n][m] (4MB)

    convert_kernel<<<6672, 256, 0, stream>>>(x_k, y_q, Lam_x, Theta_x, Lam_y,
        Lam_zy, Lam_zx, Theta_y, xkb, yqb, WxTb, WyTb, Zyb, Zxb, TyTb, ssum);

    proj_kernel<<<dim3(16, 8, 2), 256, 0, stream>>>(xkb, yqb, WxTb, WyTb,
        xtb, ytb, xvTb);

    step2_kernel<<<512, 256, 0, stream>>>(xtb, ytb, Zyb, Zxb, wzyb, wzxb, t1);

    fused_score<<<dim3(16, 32, 2), 256, 0, stream>>>(z, wzyb, wzxb, t1,
        Et, ssum);

    ogemm_kernel<<<dim3(4, 16), 256, 0, stream>>>(Et, xvTb, ssum, o2b);

    ygemm_kernel<<<dim3(8, 4, 2), 256, 0, stream>>>(o2b, TyTb, out);
}